// Round 9
// baseline (66.509 us; speedup 1.0000x reference)
//
#include <hip/hip_runtime.h>

#define HW 196
#define C  384
#define CF4 (C/4)          // 96 float4 per row
#define TK 98
#define SLICES 7
#define RPS 28             // rows per slice (7*28 = 196)

// ---------------- Read probe: pure streaming read of feature ----------
// Identical access shape to score_kernel's pass 1, no compute/LDS/score
// logic. Sinks into the scores scratch region, which score_kernel then
// deterministically overwrites in full (196*512 floats) -> output unchanged.
// Purpose: measure the read-BW ceiling for this exact pattern (dur delta
// vs R8's 45 us).
__global__ __launch_bounds__(256) void read_probe(
    const float* __restrict__ feature,
    float* __restrict__ sink)
{
    const int tid   = threadIdx.x;
    const int bid   = blockIdx.x;
    const int pair  = bid / SLICES;
    const int slice = bid - pair * SLICES;
    const int g     = tid >> 3;
    const int l8    = tid & 7;

    const float4* f4base = (const float4*)(feature + (size_t)pair * (HW * C));
    float4 acc = make_float4(0.f, 0.f, 0.f, 0.f);
    if (g < RPS) {
        const int r = slice * RPS + g;
        const float4* fr = f4base + (size_t)r * CF4 + l8;
        #pragma unroll
        for (int k = 0; k < 12; ++k) {
            float4 a = fr[8 * k];
            acc.x += a.x; acc.y += a.y; acc.z += a.z; acc.w += a.w;
        }
    }
    // keep loads live; slot is overwritten by score_kernel afterwards
    sink[((size_t)bid * 256 + tid) % ((size_t)512 * HW)] =
        (acc.x + acc.y) + (acc.z + acc.w);
}

// ---------------- Kernel A: scores (pure streaming) ----------------
__global__ __launch_bounds__(256) void score_kernel(
    const float* __restrict__ token,
    const float* __restrict__ feature,
    float* __restrict__ scores)
{
    __shared__ float4 tokLds[CF4];

    const int tid   = threadIdx.x;
    const int bid   = blockIdx.x;
    const int pair  = bid / SLICES;
    const int slice = bid - pair * SLICES;
    const int g     = tid >> 3;        // group 0..31
    const int l8    = tid & 7;

    const float* tokp = token + (size_t)pair * C;
    const float4* f4base = (const float4*)(feature + (size_t)pair * (HW * C));

    if (tid < CF4) tokLds[tid] = ((const float4*)tokp)[tid];
    __syncthreads();

    const bool active = (g < RPS);
    const int  r = slice * RPS + g;    // 0..195
    const float4* fr = f4base + (size_t)r * CF4 + l8;

    float4 a[12];
    if (active) {
        #pragma unroll
        for (int k = 0; k < 12; ++k) a[k] = fr[8 * k];   // 12 independent 16B loads
        float4 acc = make_float4(0.f, 0.f, 0.f, 0.f);
        #pragma unroll
        for (int k = 0; k < 12; ++k) {
            float4 t = tokLds[l8 + 8 * k];
            acc.x += a[k].x * t.x; acc.y += a[k].y * t.y;
            acc.z += a[k].z * t.z; acc.w += a[k].w * t.w;
        }
        float s = (acc.x + acc.y) + (acc.z + acc.w);
        s += __shfl_xor(s, 1, 64);
        s += __shfl_xor(s, 2, 64);
        s += __shfl_xor(s, 4, 64);
        if (l8 == 0)
            scores[(size_t)pair * HW + r] = s * 0.05103103630798288f; // *384^-0.5
    }
}

// ---------------- Kernel B: select + weighted sum ----------------
#define NT 512
#define NWAVE (NT/64)      // 8

__global__ __launch_bounds__(NT) void select_kernel(
    const float* __restrict__ feature,
    const float* __restrict__ scores_g,
    float* __restrict__ out)
{
    __shared__ float score[HW];
    __shared__ float selW[TK];
    __shared__ int   selIdx[TK];
    __shared__ float wsum[NWAVE];
    __shared__ int   rank2[2 * HW];
    __shared__ float part[NWAVE][C];
    __shared__ float s_max, s_winv;

    const int tid  = threadIdx.x;
    const int wave = tid >> 6;
    const int lane = tid & 63;
    const int pair = blockIdx.x;

    const float4* f4base = (const float4*)(feature + (size_t)pair * (HW * C));

    if (tid < HW) score[tid] = scores_g[(size_t)pair * HW + tid];
    __syncthreads();

    if (tid < 2 * HW) {
        const int i = tid >> 1, h = tid & 1;
        const float si = score[i];
        int cnt = 0;
        const int j0 = h * (HW / 2);
        for (int j = j0; j < j0 + HW / 2; ++j) {
            const float sj = score[j];
            cnt += (int)((sj > si) | ((sj == si) & (j < i)));
        }
        rank2[tid] = cnt;
    } else if (wave == NWAVE - 1) {
        float m = -3.4e38f;
        for (int i = lane; i < HW; i += 64) m = fmaxf(m, score[i]);
        #pragma unroll
        for (int off = 32; off > 0; off >>= 1)
            m = fmaxf(m, __shfl_xor(m, off, 64));
        if (lane == 0) s_max = m;
    }
    __syncthreads();

    float w = 0.f;
    if (tid < HW) {
        const int rank = rank2[2 * tid] + rank2[2 * tid + 1];
        if (rank < TK) {
            w = __expf(score[tid] - s_max);
            selIdx[rank] = tid;
            selW[rank]  = w;
        }
    }
    #pragma unroll
    for (int off = 32; off > 0; off >>= 1) w += __shfl_xor(w, off, 64);
    if (lane == 0) wsum[wave] = w;
    __syncthreads();
    if (tid == 0) {
        float s = 0.f;
        #pragma unroll
        for (int i = 0; i < NWAVE; ++i) s += wsum[i];
        s_winv = 1.f / s;
    }
    __syncthreads();

    float4 acc_a = make_float4(0.f, 0.f, 0.f, 0.f);
    float4 acc_b = make_float4(0.f, 0.f, 0.f, 0.f);
    #pragma unroll
    for (int j = 0; j < 12; ++j) {
        const int i = wave + NWAVE * j;          // 0..95
        const int   r   = selIdx[i];
        const float wgt = selW[i];
        const float4* f4 = f4base + (size_t)r * CF4;
        float4 aa = f4[lane];
        acc_a.x += wgt * aa.x; acc_a.y += wgt * aa.y;
        acc_a.z += wgt * aa.z; acc_a.w += wgt * aa.w;
        if (lane < 32) {
            float4 bb = f4[64 + lane];
            acc_b.x += wgt * bb.x; acc_b.y += wgt * bb.y;
            acc_b.z += wgt * bb.z; acc_b.w += wgt * bb.w;
        }
    }
    if (wave < TK - 96) {                         // rows 96, 97
        const int i = 96 + wave;
        const int   r   = selIdx[i];
        const float wgt = selW[i];
        const float4* f4 = f4base + (size_t)r * CF4;
        float4 aa = f4[lane];
        acc_a.x += wgt * aa.x; acc_a.y += wgt * aa.y;
        acc_a.z += wgt * aa.z; acc_a.w += wgt * aa.w;
        if (lane < 32) {
            float4 bb = f4[64 + lane];
            acc_b.x += wgt * bb.x; acc_b.y += wgt * bb.y;
            acc_b.z += wgt * bb.z; acc_b.w += wgt * bb.w;
        }
    }
    float4* pw = (float4*)&part[wave][0];
    pw[lane] = acc_a;
    if (lane < 32) pw[64 + lane] = acc_b;
    __syncthreads();

    if (tid < C) {
        float s = 0.f;
        #pragma unroll
        for (int wv = 0; wv < NWAVE; ++wv) s += part[wv][tid];
        out[(size_t)pair * C + tid] = s * s_winv;
    }
}

extern "C" void kernel_launch(void* const* d_in, const int* in_sizes, int n_in,
                              void* d_out, int out_size, void* d_ws, size_t ws_size,
                              hipStream_t stream) {
    const float* token   = (const float*)d_in[0];
    const float* feature = (const float*)d_in[1];
    float* out    = (float*)d_out;
    float* scores = (float*)d_ws;        // 512*196*4 B = 401 KB scratch
    const int pairs = in_sizes[0] / C;   // 8*16*4 = 512

    // measurement probe: pure read of feature in pass-1's exact shape;
    // sink region is fully overwritten by score_kernel below.
    read_probe<<<pairs * SLICES, 256, 0, stream>>>(feature, scores);
    score_kernel<<<pairs * SLICES, 256, 0, stream>>>(token, feature, scores);
    select_kernel<<<pairs, NT, 0, stream>>>(feature, scores, out);
}

// Round 10
// 43.147 us; speedup vs baseline: 1.5414x; 1.5414x over previous
//
#include <hip/hip_runtime.h>

#define HW 196
#define C  384
#define CF4 (C/4)          // 96 float4 per row
#define TK 98
#define NT 256
#define NWAVE (NT/64)      // 4

__global__ __launch_bounds__(NT) void sampling_kernel(
    const float* __restrict__ token,
    const float* __restrict__ feature,
    float* __restrict__ out)
{
    __shared__ float4 tokLds[CF4];
    __shared__ float score[HW];
    __shared__ float selW[TK];
    __shared__ int   selIdx[TK];
    __shared__ float wsum[NWAVE];
    __shared__ float part[NWAVE][C];   // 6 KB
    __shared__ float s_winv;

    const int tid  = threadIdx.x;
    const int wave = tid >> 6;
    const int lane = tid & 63;
    const int l8   = lane & 7;          // sub-lane within 8-lane group
    const int grp  = tid >> 3;          // group 0..31 in block
    const int pair = blockIdx.x;

    const float* tokp = token + (size_t)pair * C;
    const float4* f4base = (const float4*)(feature + (size_t)pair * (HW * C));

    // stage token (1.5 KB)
    if (tid < CF4) tokLds[tid] = ((const float4*)tokp)[tid];
    __syncthreads();

    const float scale = 0.05103103630798288f;  // 384^-0.5

    // ---- pass 1: 8-lane group per row; 32 groups -> 6 iters + 4-row tail.
    // 12 independent float4 loads/lane; token from LDS (keeps VGPR low ->
    // high occupancy -> cross-block phase overlap). ----
    #pragma unroll
    for (int it = 0; it < 6; ++it) {
        const int r = it * 32 + grp;                    // 0..191
        const float4* fr = f4base + (size_t)r * CF4 + l8;
        float4 a[12];
        #pragma unroll
        for (int k = 0; k < 12; ++k) a[k] = fr[8 * k];
        float4 acc = make_float4(0.f, 0.f, 0.f, 0.f);
        #pragma unroll
        for (int k = 0; k < 12; ++k) {
            float4 t = tokLds[l8 + 8 * k];
            acc.x += a[k].x * t.x; acc.y += a[k].y * t.y;
            acc.z += a[k].z * t.z; acc.w += a[k].w * t.w;
        }
        float s = (acc.x + acc.y) + (acc.z + acc.w);
        s += __shfl_xor(s, 1, 64);
        s += __shfl_xor(s, 2, 64);
        s += __shfl_xor(s, 4, 64);
        if (l8 == 0) score[r] = s * scale;
    }
    if (grp < 4) {                                      // tail rows 192..195
        const int r = 192 + grp;
        const float4* fr = f4base + (size_t)r * CF4 + l8;
        float4 acc = make_float4(0.f, 0.f, 0.f, 0.f);
        #pragma unroll
        for (int k = 0; k < 12; ++k) {
            float4 a = fr[8 * k];
            float4 t = tokLds[l8 + 8 * k];
            acc.x += a.x * t.x; acc.y += a.y * t.y;
            acc.z += a.z * t.z; acc.w += a.w * t.w;
        }
        float s = (acc.x + acc.y) + (acc.z + acc.w);
        s += __shfl_xor(s, 1, 64);
        s += __shfl_xor(s, 2, 64);
        s += __shfl_xor(s, 4, 64);
        if (l8 == 0) score[r] = s * scale;
    }
    __syncthreads();

    // ---- rank-by-counting with FUSED max (each thread scans all 196
    // scores anyway). jax.lax.top_k stable tie-break; softmax denom
    // cancels under renormalization: w = exp(s - max). ----
    float w = 0.f;
    if (tid < HW) {
        const float si = score[tid];
        int   rank = 0;
        float m    = -3.4e38f;
        for (int j = 0; j < HW; ++j) {
            const float sj = score[j];                 // LDS broadcast
            rank += (int)((sj > si) | ((sj == si) & (j < tid)));
            m = fmaxf(m, sj);
        }
        if (rank < TK) {
            w = __expf(si - m);
            selIdx[rank] = tid;
            selW[rank]  = w;
        }
    }
    #pragma unroll
    for (int off = 32; off > 0; off >>= 1) w += __shfl_xor(w, off, 64);
    if (lane == 0) wsum[wave] = w;
    __syncthreads();
    if (tid == 0)
        s_winv = 1.f / (wsum[0] + wsum[1] + wsum[2] + wsum[3]);
    __syncthreads();

    // ---- pass 2: weighted sum over 98 selected rows (L3-warm).
    // 4 waves x 24 static iters + 2-row tail; full-wave coalesced rows. ----
    float4 acc_a = make_float4(0.f, 0.f, 0.f, 0.f);
    float4 acc_b = make_float4(0.f, 0.f, 0.f, 0.f);
    #pragma unroll
    for (int j = 0; j < 24; ++j) {
        const int i = wave + NWAVE * j;          // 0..95
        const int   r   = selIdx[i];
        const float wgt = selW[i];
        const float4* f4 = f4base + (size_t)r * CF4;
        float4 aa = f4[lane];
        acc_a.x += wgt * aa.x; acc_a.y += wgt * aa.y;
        acc_a.z += wgt * aa.z; acc_a.w += wgt * aa.w;
        if (lane < 32) {
            float4 bb = f4[64 + lane];
            acc_b.x += wgt * bb.x; acc_b.y += wgt * bb.y;
            acc_b.z += wgt * bb.z; acc_b.w += wgt * bb.w;
        }
    }
    if (wave < TK - 96) {                         // rows 96, 97
        const int i = 96 + wave;
        const int   r   = selIdx[i];
        const float wgt = selW[i];
        const float4* f4 = f4base + (size_t)r * CF4;
        float4 aa = f4[lane];
        acc_a.x += wgt * aa.x; acc_a.y += wgt * aa.y;
        acc_a.z += wgt * aa.z; acc_a.w += wgt * aa.w;
        if (lane < 32) {
            float4 bb = f4[64 + lane];
            acc_b.x += wgt * bb.x; acc_b.y += wgt * bb.y;
            acc_b.z += wgt * bb.z; acc_b.w += wgt * bb.w;
        }
    }
    float4* pw = (float4*)&part[wave][0];
    pw[lane] = acc_a;
    if (lane < 32) pw[64 + lane] = acc_b;
    __syncthreads();

    // ---- 4-way cross-wave reduction, coalesced store (2 sweeps of 256) ----
    for (int c = tid; c < C; c += NT) {
        float s = (part[0][c] + part[1][c]) + (part[2][c] + part[3][c]);
        out[(size_t)pair * C + c] = s * s_winv;
    }
}

extern "C" void kernel_launch(void* const* d_in, const int* in_sizes, int n_in,
                              void* d_out, int out_size, void* d_ws, size_t ws_size,
                              hipStream_t stream) {
    const float* token   = (const float*)d_in[0];
    const float* feature = (const float*)d_in[1];
    float* out = (float*)d_out;
    const int pairs = in_sizes[0] / C;   // 8*16*4 = 512
    sampling_kernel<<<pairs, NT, 0, stream>>>(token, feature, out);
}

// Round 11
// 36.872 us; speedup vs baseline: 1.8038x; 1.1702x over previous
//
#include <hip/hip_runtime.h>
#include <hip/hip_fp16.h>

#define HW 196
#define C  384
#define CF4 (C/4)          // 96 float4 per row
#define TK 98
#define NT 512
#define NWAVE (NT/64)      // 8

__global__ __launch_bounds__(NT, 4) void sampling_kernel(
    const float* __restrict__ token,
    const float* __restrict__ feature,
    float* __restrict__ out)
{
    // fp16 stash of rows 0..97 (73.5 KB). Total LDS ~78 KB -> 2 blocks/CU.
    // After pass-2 accumulation this region is reused (post-barrier) for
    // the cross-wave partials.
    __shared__ __align__(16) unsigned char stash_raw[TK * C * 2];
    __shared__ float tokLds[C];
    __shared__ float score[HW];
    __shared__ float selW[TK];
    __shared__ int   selIdx[TK];
    __shared__ float wsum[NWAVE];
    __shared__ int   rank2[2 * HW];
    __shared__ float s_max, s_winv;

    __half (*feat16)[C] = (__half(*)[C])stash_raw;
    float  (*part)[C]   = (float(*)[C])stash_raw;   // aliased, barrier-fenced

    const int tid  = threadIdx.x;
    const int wave = tid >> 6;
    const int lane = tid & 63;
    const int l8   = lane & 7;         // sub-lane within 8-lane group
    const int g8   = lane >> 3;        // group 0..7 within wave
    const int pair = blockIdx.x;

    const float* tokp  = token   + (size_t)pair * C;
    const float* featp = feature + (size_t)pair * (HW * C);
    const float4* f4base = (const float4*)featp;
    const float4* t4     = (const float4*)tokLds;

    // stage token row (384 f32) in LDS
    for (int i = tid; i < C; i += NT) tokLds[i] = tokp[i];
    __syncthreads();

    // this lane's token column-slice in registers: cols 4*l8+32k
    float4 tok[12];
    #pragma unroll
    for (int k = 0; k < 12; ++k) tok[k] = t4[l8 + 8 * k];

    const float scale = 0.05103103630798288f;  // 384^-0.5

    // ---- pass 1: 8-lane group per row; 64 groups -> 3 balanced iters.
    // 12 independent float4 loads/lane; rows < 98 additionally stashed
    // to LDS as fp16 (data already in registers -> free bandwidth-wise).
    #pragma unroll
    for (int it = 0; it < 3; ++it) {
        const int r = it * 64 + wave * 8 + g8;          // 0..191, balanced
        const float4* fr = f4base + (size_t)r * CF4 + l8;
        float4 a[12];
        #pragma unroll
        for (int k = 0; k < 12; ++k) a[k] = fr[8 * k];
        float4 acc = make_float4(0.f, 0.f, 0.f, 0.f);
        #pragma unroll
        for (int k = 0; k < 12; ++k) {
            acc.x += a[k].x * tok[k].x; acc.y += a[k].y * tok[k].y;
            acc.z += a[k].z * tok[k].z; acc.w += a[k].w * tok[k].w;
        }
        if (r < TK) {
            #pragma unroll
            for (int k = 0; k < 12; ++k) {
                union { uint2 u; __half2 h[2]; } W;
                W.h[0] = __floats2half2_rn(a[k].x, a[k].y);
                W.h[1] = __floats2half2_rn(a[k].z, a[k].w);
                *(uint2*)&feat16[r][4 * l8 + 32 * k] = W.u;
            }
        }
        float s = (acc.x + acc.y) + (acc.z + acc.w);
        s += __shfl_xor(s, 1, 64);
        s += __shfl_xor(s, 2, 64);
        s += __shfl_xor(s, 4, 64);
        if (l8 == 0) score[r] = s * scale;
    }
    // tail rows 192..195 (all >= 98, no stash)
    if (wave < 4 && g8 == 0) {
        const int r = 192 + wave;
        const float4* fr = f4base + (size_t)r * CF4 + l8;
        float4 acc = make_float4(0.f, 0.f, 0.f, 0.f);
        #pragma unroll
        for (int k = 0; k < 12; ++k) {
            float4 a = fr[8 * k];
            acc.x += a.x * tok[k].x; acc.y += a.y * tok[k].y;
            acc.z += a.z * tok[k].z; acc.w += a.w * tok[k].w;
        }
        float s = (acc.x + acc.y) + (acc.z + acc.w);
        s += __shfl_xor(s, 1, 64);
        s += __shfl_xor(s, 2, 64);
        s += __shfl_xor(s, 4, 64);
        if (l8 == 0) score[r] = s * scale;
    }
    __syncthreads();

    // ---- concurrent: threads 0..391 rank-count (half-range each);
    //      wave 7 computes the max. (R6 verbatim) ----
    if (tid < 2 * HW) {
        const int i = tid >> 1, h = tid & 1;
        const float si = score[i];
        int cnt = 0;
        const int j0 = h * (HW / 2);
        for (int j = j0; j < j0 + HW / 2; ++j) {
            const float sj = score[j];
            cnt += (int)((sj > si) | ((sj == si) & (j < i)));
        }
        rank2[tid] = cnt;
    } else if (wave == NWAVE - 1) {
        float m = -3.4e38f;
        for (int i = lane; i < HW; i += 64) m = fmaxf(m, score[i]);
        #pragma unroll
        for (int off = 32; off > 0; off >>= 1)
            m = fmaxf(m, __shfl_xor(m, off, 64));
        if (lane == 0) s_max = m;
    }
    __syncthreads();

    // ---- select + compact (softmax denom cancels: w = exp(s - max)) ----
    float w = 0.f;
    if (tid < HW) {
        const int rank = rank2[2 * tid] + rank2[2 * tid + 1];
        if (rank < TK) {
            w = __expf(score[tid] - s_max);
            selIdx[rank] = tid;
            selW[rank]  = w;
        }
    }
    #pragma unroll
    for (int off = 32; off > 0; off >>= 1) w += __shfl_xor(w, off, 64);
    if (lane == 0) wsum[wave] = w;
    __syncthreads();
    if (tid == 0) {
        float s = 0.f;
        #pragma unroll
        for (int i = 0; i < NWAVE; ++i) s += wsum[i];
        s_winv = 1.f / s;
    }
    __syncthreads();

    // ---- pass 2: weighted sum over 98 selected rows.
    // idx < 98 -> fp16 LDS stash; idx >= 98 -> global (L3-warm).
    // Row index is wave-uniform -> branch is wave-uniform. ----
    float4 acc_a = make_float4(0.f, 0.f, 0.f, 0.f);
    float4 acc_b = make_float4(0.f, 0.f, 0.f, 0.f);
    #pragma unroll
    for (int j = 0; j < 13; ++j) {
        const int i = wave + NWAVE * j;          // 0..103
        if (i < TK) {
            const int   r   = selIdx[i];
            const float wgt = selW[i];
            if (r < TK) {
                union { uint2 u; __half2 h[2]; } U;
                U.u = *(const uint2*)&feat16[r][4 * lane];
                float2 f0 = __half22float2(U.h[0]);
                float2 f1 = __half22float2(U.h[1]);
                acc_a.x += wgt * f0.x; acc_a.y += wgt * f0.y;
                acc_a.z += wgt * f1.x; acc_a.w += wgt * f1.y;
                if (lane < 32) {
                    union { uint2 u; __half2 h[2]; } V;
                    V.u = *(const uint2*)&feat16[r][256 + 4 * lane];
                    float2 g0 = __half22float2(V.h[0]);
                    float2 g1 = __half22float2(V.h[1]);
                    acc_b.x += wgt * g0.x; acc_b.y += wgt * g0.y;
                    acc_b.z += wgt * g1.x; acc_b.w += wgt * g1.y;
                }
            } else {
                const float4* f4 = f4base + (size_t)r * CF4;
                float4 aa = f4[lane];
                acc_a.x += wgt * aa.x; acc_a.y += wgt * aa.y;
                acc_a.z += wgt * aa.z; acc_a.w += wgt * aa.w;
                if (lane < 32) {
                    float4 bb = f4[64 + lane];
                    acc_b.x += wgt * bb.x; acc_b.y += wgt * bb.y;
                    acc_b.z += wgt * bb.z; acc_b.w += wgt * bb.w;
                }
            }
        }
    }
    // all stash reads complete before the region is reused for partials
    __syncthreads();

    float4* pw = (float4*)&part[wave][0];
    pw[lane] = acc_a;
    if (lane < 32) pw[64 + lane] = acc_b;
    __syncthreads();

    // ---- 8-way cross-wave reduction, coalesced store ----
    if (tid < C) {
        float s = 0.f;
        #pragma unroll
        for (int wv = 0; wv < NWAVE; ++wv) s += part[wv][tid];
        out[(size_t)pair * C + tid] = s * s_winv;
    }
}

extern "C" void kernel_launch(void* const* d_in, const int* in_sizes, int n_in,
                              void* d_out, int out_size, void* d_ws, size_t ws_size,
                              hipStream_t stream) {
    const float* token   = (const float*)d_in[0];
    const float* feature = (const float*)d_in[1];
    float* out = (float*)d_out;
    const int pairs = in_sizes[0] / C;   // 8*16*4 = 512
    sampling_kernel<<<pairs, NT, 0, stream>>>(token, feature, out);
}